// Round 4
// baseline (418.339 us; speedup 1.0000x reference)
//
#include <hip/hip_runtime.h>
#include <stdint.h>

typedef int v4i  __attribute__((ext_vector_type(4)));
typedef int v16i __attribute__((ext_vector_type(16)));

#define M_TOK 8192
#define N_OUT 4096
#define K_IN  4096

// -------------------------------------------------------------------------
// Pack: A -> row-major int8 (coalesced). W -> B' fragment-major int8:
//   B'[n32][c][lane] (16B units), lane encodes (n=n32*32+(lane&31),
//   k16 = c*2 + (lane>>5)), so the GEMM's B-fragment load is one fully
//   coalesced 1KB global_load_dwordx4 per (wave, n-chunk, k-granule-pair).
// -------------------------------------------------------------------------
__device__ __forceinline__ int pack4(int4 a) {
    return (a.x & 255) | ((a.y & 255) << 8) | ((a.z & 255) << 16) | ((a.w & 255) << 24);
}

__global__ __launch_bounds__(256) void pack_kernel(
    const int4* __restrict__ x, const int* __restrict__ w,
    int* __restrict__ dA, int4* __restrict__ dBp, int n4x, int nB16)
{
    int i = blockIdx.x * blockDim.x + threadIdx.x;
    if (i < n4x) {
        dA[i] = pack4(x[i]);
    } else {
        int t = i - n4x;
        if (t < nB16) {
            int lane = t & 63;
            int c    = (t >> 6) & 127;          // K granule-pair index (32 int8)
            int n32  = t >> 13;                 // 32-row N chunk
            int row  = n32 * 32 + (lane & 31);
            int col  = c * 32 + (lane >> 5) * 16;
            const int4* src = (const int4*)(w + (size_t)row * K_IN + col);
            int4 p;
            p.x = pack4(src[0]);
            p.y = pack4(src[1]);
            p.z = pack4(src[2]);
            p.w = pack4(src[3]);
            dBp[t] = p;                          // coalesced 16B store
        }
    }
}

// -------------------------------------------------------------------------
// i8 GEMM: C[M,N] = A[M,K].B[N,K]^T. 128x128 tile, BK=128, 4 waves (2x2),
// wave = 64x64 via 2x2 mfma_i32_32x32x32_i8.
//  - A: LDS, double-buffered (2x16KB), global_load_lds w=16, XOR-swizzled.
//  - B: NO LDS — direct global->reg from pre-swizzled B', reg double-buffer.
//  - ONE barrier per K-iter; next iter's A-staging + B-loads issued before
//    compute so their latency hides under the MFMAs.
// R3 history: both-in-LDS BK=128 = 159.5us, MfmaUtil 40% — LDS-pipe-bound
// (conflict counter = 32 x staging instrs; frag reads 64KB/blk-iter).
// -------------------------------------------------------------------------
__global__ __launch_bounds__(256) void gemm_i8_kernel(
    const char* __restrict__ A8,       // [M][K] int8 row-major
    const int*  __restrict__ Bp,       // B' fragment-major
    const float* __restrict__ scale_ptr,
    float* __restrict__ out)           // [M][N] float + 1 scalar
{
    __shared__ alignas(16) char lA[2][128 * 128];   // 2 x 16 KB

    const int tid  = threadIdx.x;
    const int wave = tid >> 6;
    const int lane = tid & 63;

    const int bm = blockIdx.x * 128;   // x-major: consecutive blocks share bn
    const int bn = blockIdx.y * 128;

    const int wm = (wave >> 1) * 64;
    const int wn = (wave & 1) * 64;

    v16i acc[2][2];
#pragma unroll
    for (int i = 0; i < 2; ++i)
#pragma unroll
        for (int j = 0; j < 2; ++j)
#pragma unroll
            for (int r = 0; r < 16; ++r)
                acc[i][j][r] = 0;

    // ---- A staging: wave stages rows [32*wave, 32*wave+32), 4 chunks of
    // 8 rows x 128B. Global column granule XOR-swizzled by row&7 so the
    // fragment reads are bank-conflict-free.
    const int srow = lane >> 3;
    const int scol = ((lane & 7) ^ srow) << 4;

    const char* gA[4];
    char* lp0[4];
    char* lp1[4];
#pragma unroll
    for (int q = 0; q < 4; ++q) {
        int row0 = wave * 32 + q * 8;
        gA[q]  = A8 + (size_t)(bm + row0 + srow) * K_IN + scol;
        lp0[q] = lA[0] + row0 * 128;
        lp1[q] = lA[1] + row0 * 128;
    }

    // ---- B' base for this wave: v4i index = ((n32)*128 + c)*64 + lane
    const v4i* Bb = (const v4i*)Bp + (size_t)((bn >> 5) + (wn >> 5)) * (128 * 64) + lane;

    // ---- fragment geometry (32x32x32): A[m=lane&31][k=(lane>>5)*16+j]
    const int fm  = lane & 31;
    const int fh  = lane >> 5;
    const int fsw = fm & 7;

    v4i b0[8], b1[8];

    // ---- prologue: prefetch k0 = 0
#pragma unroll
    for (int t = 0; t < 2; ++t)
#pragma unroll
        for (int kk = 0; kk < 4; ++kk)
            b0[t * 4 + kk] = Bb[(size_t)(t * 128 + kk) * 64];
#pragma unroll
    for (int q = 0; q < 4; ++q)
        __builtin_amdgcn_global_load_lds(
            (const __attribute__((address_space(1))) void*)(gA[q]),
            (__attribute__((address_space(3))) void*)lp0[q], 16, 0, 0);
    __syncthreads();

#pragma unroll 1
    for (int k0 = 0; k0 < K_IN; k0 += 256) {
        // ======== even half: compute lA[0]/b0, prefetch k0+128 -> lA[1]/b1
        {
            const int kn = (k0 + 128) & (K_IN - 1);
            const int cn = kn >> 5;
#pragma unroll
            for (int t = 0; t < 2; ++t)
#pragma unroll
                for (int kk = 0; kk < 4; ++kk)
                    b1[t * 4 + kk] = Bb[(size_t)(t * 128 + cn + kk) * 64];
#pragma unroll
            for (int q = 0; q < 4; ++q)
                __builtin_amdgcn_global_load_lds(
                    (const __attribute__((address_space(1))) void*)(gA[q] + kn),
                    (__attribute__((address_space(3))) void*)lp1[q], 16, 0, 0);
#pragma unroll
            for (int kk = 0; kk < 4; ++kk) {
                const int goff = ((kk * 2 + fh) ^ fsw) << 4;
                v4i af0 = *(const v4i*)(lA[0] + (wm + fm) * 128 + goff);
                v4i af1 = *(const v4i*)(lA[0] + (wm + 32 + fm) * 128 + goff);
                acc[0][0] = __builtin_amdgcn_mfma_i32_32x32x32_i8(af0, b0[kk],     acc[0][0], 0, 0, 0);
                acc[0][1] = __builtin_amdgcn_mfma_i32_32x32x32_i8(af0, b0[4 + kk], acc[0][1], 0, 0, 0);
                acc[1][0] = __builtin_amdgcn_mfma_i32_32x32x32_i8(af1, b0[kk],     acc[1][0], 0, 0, 0);
                acc[1][1] = __builtin_amdgcn_mfma_i32_32x32x32_i8(af1, b0[4 + kk], acc[1][1], 0, 0, 0);
            }
            __syncthreads();
        }
        // ======== odd half: compute lA[1]/b1, prefetch k0+256 -> lA[0]/b0
        {
            const int kn = (k0 + 256) & (K_IN - 1);
            const int cn = kn >> 5;
#pragma unroll
            for (int t = 0; t < 2; ++t)
#pragma unroll
                for (int kk = 0; kk < 4; ++kk)
                    b0[t * 4 + kk] = Bb[(size_t)(t * 128 + cn + kk) * 64];
#pragma unroll
            for (int q = 0; q < 4; ++q)
                __builtin_amdgcn_global_load_lds(
                    (const __attribute__((address_space(1))) void*)(gA[q] + kn),
                    (__attribute__((address_space(3))) void*)lp0[q], 16, 0, 0);
#pragma unroll
            for (int kk = 0; kk < 4; ++kk) {
                const int goff = ((kk * 2 + fh) ^ fsw) << 4;
                v4i af0 = *(const v4i*)(lA[1] + (wm + fm) * 128 + goff);
                v4i af1 = *(const v4i*)(lA[1] + (wm + 32 + fm) * 128 + goff);
                acc[0][0] = __builtin_amdgcn_mfma_i32_32x32x32_i8(af0, b1[kk],     acc[0][0], 0, 0, 0);
                acc[0][1] = __builtin_amdgcn_mfma_i32_32x32x32_i8(af0, b1[4 + kk], acc[0][1], 0, 0, 0);
                acc[1][0] = __builtin_amdgcn_mfma_i32_32x32x32_i8(af1, b1[kk],     acc[1][0], 0, 0, 0);
                acc[1][1] = __builtin_amdgcn_mfma_i32_32x32x32_i8(af1, b1[4 + kk], acc[1][1], 0, 0, 0);
            }
            __syncthreads();
        }
    }

    // ---- epilogue: y = clip(rint(acc * scale), -128, 127) as float
    // 32x32 C/D: col = lane&31, row = (r&3) + 8*(r>>2) + 4*(lane>>5)
    const float s     = scale_ptr[0];
    const float scale = (s * 0.1f) / 0.1f;

#pragma unroll
    for (int ti = 0; ti < 2; ++ti) {
#pragma unroll
        for (int tj = 0; tj < 2; ++tj) {
#pragma unroll
            for (int r = 0; r < 16; ++r) {
                int row = bm + wm + ti * 32 + (r & 3) + 8 * (r >> 2) + 4 * fh;
                int col = bn + wn + tj * 32 + fm;
                float y = (float)acc[ti][tj][r] * scale;
                y = rintf(y);
                y = fminf(fmaxf(y, -128.0f), 127.0f);
                out[(size_t)row * N_OUT + col] = y;
            }
        }
    }

    if (bm == 0 && bn == 0 && tid == 0)
        out[(size_t)M_TOK * N_OUT] = 0.1f;
}

// -------------------------------------------------------------------------
extern "C" void kernel_launch(void* const* d_in, const int* in_sizes, int n_in,
                              void* d_out, int out_size, void* d_ws, size_t ws_size,
                              hipStream_t stream)
{
    const int*   x_q     = (const int*)d_in[0];
    const int*   w_q     = (const int*)d_in[1];
    const float* scale_x = (const float*)d_in[2];
    float* out = (float*)d_out;

    char* A8 = (char*)d_ws;                              // 32 MB
    char* Bp = (char*)d_ws + (size_t)M_TOK * K_IN;       // 16 MB (B')

    const int n4x  = (M_TOK * K_IN) / 4;    // 8388608 A chunks (4B out)
    const int nB16 = (N_OUT * K_IN) / 16;   // 1048576 B chunks (16B out)

    pack_kernel<<<(n4x + nB16 + 255) / 256, 256, 0, stream>>>(
        (const int4*)x_q, w_q, (int*)A8, (int4*)Bp, n4x, nB16);

    // x-major grid: 64 consecutive blocks share bn -> B' panel L2-resident
    dim3 grid(M_TOK / 128, N_OUT / 128);   // (64, 32)
    gemm_i8_kernel<<<grid, 256, 0, stream>>>(A8, (const int*)Bp, scale_x, out);
}